// Round 13
// baseline (2836.302 us; speedup 1.0000x reference)
//
#include <hip/hip_runtime.h>
#include <stdint.h>

// ============================================================================
// ConViTCast: B=2 V=5 H=32 W=64 P=2 D=1024 NH=16 hd=64 DEPTH=2 L=512 BL=1024
// R11 this session: v15 — v14 (2763us) + k_og G4 token-batching.
// v14 evidence: bf16 k_mg conversion passed (absmax 0.00195, 2 quanta).
// Model (no rocprof 2 rounds): ODE ~1.9ms of 2.76 = 80 phases x ~24us; k_og
// floor = per-CU L1 traffic (512KB weight slice + 32KB act per block,
// ~64B/cy -> ~3.5us) + 3 launches/phase.
// v15: k_og batches 4 token-groups/block (64 tokens x 64 cols): block
// (gp 0..15, cs 0..15); wave wv -> group gp*4+(wv>>2), ct cs*4+(wv&3).
// Per-block unique weights 512->128KB (4 waves share frags via L1, 4KB/kk
// working set), act LDS 32->128KB (<160). Per-CU bytes 544->256KB.
// Arithmetic BIT-IDENTICAL (same frags, same kk order) -> absmax unchanged.
// Predict: k_og ~3.5->2us, phase ~24->19us, total 2763 -> ~2400-2550us.
// If flat: launch overhead dominates -> cut kernels/phase or MFMA attn next.
// [R12: identical resubmit — GPUAcquisitionTimeout. Audit re-confirmed G4
//  coverage, staging quarters, 128KB LDS fit, bit-identity of MFMA path.]
// ============================================================================

#define NSTEPS 10
#define RESF 0.01f
#define EPSF 1e-5f

typedef unsigned short u16;
typedef unsigned int u32;
typedef __attribute__((ext_vector_type(8))) short bf16x8;
typedef __attribute__((ext_vector_type(4))) float f32x4;

// s_waitcnt vmcnt(N), ignore exp/lgkm (gfx9 encoding: vm[3:0]|[15:14], exp=7, lgkm=15)
#define VMCNT(N) __builtin_amdgcn_s_waitcnt(0x0F70 | ((N) & 0xF) | ((((N) >> 4) & 0x3) << 14))

__device__ __forceinline__ float b2f(u16 u) {
  return __uint_as_float(((uint32_t)u) << 16);
}
__device__ __forceinline__ u16 f2b(float f) {
  uint32_t x = __float_as_uint(f);
  uint32_t r = x + 0x7fffu + ((x >> 16) & 1u);  // round-to-nearest-even
  return (u16)(r >> 16);
}
__device__ __forceinline__ float red16(float v) {
  v += __shfl_xor(v, 1); v += __shfl_xor(v, 2);
  v += __shfl_xor(v, 4); v += __shfl_xor(v, 8);
  return v;
}

// Repack f32 weight [Ncols][1024 k] -> bf16 MFMA-frag blob (grid = N*4 blocks):
// blob[((ct*32+kk)*64+l)*8+j] = w[ct*16+(l&15)][kk*32+(l>>4)*8+j]
__global__ __launch_bounds__(256) void k_pack(
    const float* __restrict__ in, u16* __restrict__ out16) {
  int i = blockIdx.x * 256 + threadIdx.x;
  int j = i & 7;
  int l = (i >> 3) & 63;
  int kk = (i >> 9) & 31;
  int ct = i >> 14;
  int col = ct * 16 + (l & 15);
  int k = kk * 32 + ((l >> 4) << 3) + j;
  out16[i] = f2b(in[(size_t)col * 1024 + k]);
}

// ---------------------------------------------------------------------------
// Extract patches[m*20 + v*4 + p] from x[b,v,h,w]; m=b*512+l, l=hh*32+ww
// ---------------------------------------------------------------------------
__global__ __launch_bounds__(256) void k_patches(
    const float* __restrict__ x, float* __restrict__ patches) {
  int i = blockIdx.x * 256 + threadIdx.x;  // grid 80*256 = 20480
  int m = i / 20, r = i % 20;
  int v = r >> 2, p = r & 3;
  int b = m >> 9, l = m & 511;
  int hh = l >> 5, ww = l & 31;
  int pr = p >> 1, pc = p & 1;
  patches[i] = x[((size_t)(b * 5 + v) * 32 + hh * 2 + pr) * 64 + ww * 2 + pc];
}

// qvec = var_query @ Wq^T + bq   (grid 64)
__global__ __launch_bounds__(256) void k_qvec(
    const float* __restrict__ vq, const float* __restrict__ w,
    const float* __restrict__ bias, float* __restrict__ qvec) {
  int dq = blockIdx.x * 16 + (threadIdx.x >> 4);
  int lane = threadIdx.x & 15;
  float p = 0.f;
  for (int j = 0; j < 64; j++) {
    int d = lane + 16 * j;
    p += vq[d] * w[(size_t)dq * 1024 + d];
  }
  p = red16(p);
  if (lane == 0) qvec[dq] = p + bias[dq];
}

// qb[h] = sum_e qvec[h*64+e]*bk[h*64+e]   (grid 1)
__global__ __launch_bounds__(256) void k_qb(
    const float* __restrict__ qvec, const float* __restrict__ bk,
    float* __restrict__ qb) {
  int h = threadIdx.x >> 4, lane = threadIdx.x & 15;
  float p = 0.f;
  for (int e = lane; e < 64; e += 16) p += qvec[h * 64 + e] * bk[h * 64 + e];
  p = red16(p);
  if (lane == 0) qb[h] = p;
}

// u[h][d] = sum_e qvec[h*64+e] * Wk[h*64+e][d]   (grid 64)
__global__ __launch_bounds__(256) void k_u(
    const float* __restrict__ qvec, const float* __restrict__ wk,
    float* __restrict__ u) {
  int d = blockIdx.x * 16 + (threadIdx.x & 15);
  int h = threadIdx.x >> 4;
  float acc = 0.f;
  for (int e = 0; e < 64; e++)
    acc += qvec[h * 64 + e] * wk[(size_t)(h * 64 + e) * 1024 + d];
  u[h * 1024 + d] = acc;
}

// PU[(v*16+h)*4+p] = 0.125*sum_d pw[v,d,p]*u[h,d]
// C0[v*16+h]       = 0.125*(sum_d (pb+ve)[v,d]*u[h,d] + qb[h])     (grid 80)
__global__ __launch_bounds__(256) void k_pu(
    const float* __restrict__ pw, const float* __restrict__ pb,
    const float* __restrict__ ve, const float* __restrict__ u,
    const float* __restrict__ qb, float* __restrict__ PU,
    float* __restrict__ C0) {
  int v = blockIdx.x / 16, h = blockIdx.x % 16;
  int t = threadIdx.x;
  float a0 = 0, a1 = 0, a2 = 0, a3 = 0, ac = 0;
  for (int d = t; d < 1024; d += 256) {
    float uu = u[h * 1024 + d];
    const float* p4 = pw + ((size_t)v * 1024 + d) * 4;
    a0 += p4[0] * uu; a1 += p4[1] * uu; a2 += p4[2] * uu; a3 += p4[3] * uu;
    ac += (pb[v * 1024 + d] + ve[v * 1024 + d]) * uu;
  }
  for (int off = 1; off < 64; off <<= 1) {
    a0 += __shfl_xor(a0, off); a1 += __shfl_xor(a1, off);
    a2 += __shfl_xor(a2, off); a3 += __shfl_xor(a3, off);
    ac += __shfl_xor(ac, off);
  }
  __shared__ float r[4][5];
  if ((t & 63) == 0) {
    int w = t >> 6;
    r[w][0] = a0; r[w][1] = a1; r[w][2] = a2; r[w][3] = a3; r[w][4] = ac;
  }
  __syncthreads();
  if (t == 0) {
    float s[5];
    for (int j = 0; j < 5; j++) s[j] = r[0][j] + r[1][j] + r[2][j] + r[3][j];
    float* pu = PU + (v * 16 + h) * 4;
    pu[0] = 0.125f * s[0]; pu[1] = 0.125f * s[1];
    pu[2] = 0.125f * s[2]; pu[3] = 0.125f * s[3];
    C0[v * 16 + h] = 0.125f * (s[4] + qb[h]);
  }
}

// PW[(v*1024+col)*4+p] = sum_d Wv[col,d]*pw[v,d,p]
// CV[v*1024+col]       = sum_d Wv[col,d]*(pb+ve)[v,d] + bv[col]    (grid 5120)
__global__ __launch_bounds__(256) void k_pw(
    const float* __restrict__ wv, const float* __restrict__ bv,
    const float* __restrict__ pw, const float* __restrict__ pb,
    const float* __restrict__ ve, float* __restrict__ PW,
    float* __restrict__ CV) {
  int v = blockIdx.x >> 10, col = blockIdx.x & 1023;
  int t = threadIdx.x;
  const float* wr = wv + (size_t)col * 1024;
  float4 w4 = *(const float4*)(wr + t * 4);
  float a0 = 0, a1 = 0, a2 = 0, a3 = 0, ac = 0;
#pragma unroll
  for (int j = 0; j < 4; j++) {
    int d = t * 4 + j;
    float wj = (j == 0) ? w4.x : (j == 1) ? w4.y : (j == 2) ? w4.z : w4.w;
    const float* p4 = pw + ((size_t)v * 1024 + d) * 4;
    a0 += wj * p4[0]; a1 += wj * p4[1]; a2 += wj * p4[2]; a3 += wj * p4[3];
    ac += wj * (pb[v * 1024 + d] + ve[v * 1024 + d]);
  }
  for (int off = 1; off < 64; off <<= 1) {
    a0 += __shfl_xor(a0, off); a1 += __shfl_xor(a1, off);
    a2 += __shfl_xor(a2, off); a3 += __shfl_xor(a3, off);
    ac += __shfl_xor(ac, off);
  }
  __shared__ float r[4][5];
  if ((t & 63) == 0) {
    int w = t >> 6;
    r[w][0] = a0; r[w][1] = a1; r[w][2] = a2; r[w][3] = a3; r[w][4] = ac;
  }
  __syncthreads();
  if (t == 0) {
    float s[5];
    for (int j = 0; j < 5; j++) s[j] = r[0][j] + r[1][j] + r[2][j] + r[3][j];
    float* o = PW + ((size_t)(v * 1024 + col)) * 4;
    o[0] = s[0]; o[1] = s[1]; o[2] = s[2]; o[3] = s[3];
    CV[v * 1024 + col] = s[4] + bv[col];
  }
}

// scores s[v][h] = patches[m,v]·PU[v,h] + C0[v,h]; softmax over v
// -> amat[m*80 + h*5 + v]                                          (grid 1024)
__global__ __launch_bounds__(256) void k_scoresm(
    const float* __restrict__ patches, const float* __restrict__ PU,
    const float* __restrict__ C0, float* __restrict__ amat) {
  __shared__ float pat[20];
  __shared__ float sa[16][8];
  int m = blockIdx.x, t = threadIdx.x;
  if (t < 20) pat[t] = patches[m * 20 + t];
  __syncthreads();
  if (t < 80) {
    int v = t / 16, h = t % 16;
    const float* pu = PU + (v * 16 + h) * 4;
    float s = C0[v * 16 + h] + pat[v * 4 + 0] * pu[0] + pat[v * 4 + 1] * pu[1]
            + pat[v * 4 + 2] * pu[2] + pat[v * 4 + 3] * pu[3];
    sa[h][v] = s;
  }
  __syncthreads();
  if (t < 16) {
    float mx = sa[t][0];
    for (int v = 1; v < 5; v++) mx = fmaxf(mx, sa[t][v]);
    float e[5], sum = 0.f;
    for (int v = 0; v < 5; v++) { e[v] = __expf(sa[t][v] - mx); sum += e[v]; }
    float inv = 1.f / sum;
    for (int v = 0; v < 5; v++) amat[m * 80 + t * 5 + v] = e[v] * inv;
  }
}

// agg[m,c] = sum_v amat[m,h(c),v] * (patches[m,v]·PW[v,c] + CV[v,c]) (grid 1024)
__global__ __launch_bounds__(256) void k_agg(
    const float* __restrict__ patches, const float* __restrict__ PW,
    const float* __restrict__ CV, const float* __restrict__ amat,
    float* __restrict__ agg) {
  __shared__ float pat[20];
  __shared__ float am[80];
  int m = blockIdx.x, t = threadIdx.x;
  if (t < 20) pat[t] = patches[m * 20 + t];
  if (t < 80) am[t] = amat[m * 80 + t];
  __syncthreads();
  int c0 = t * 4;
#pragma unroll
  for (int j = 0; j < 4; j++) {
    int c = c0 + j;
    int h = c >> 6;
    float acc = 0.f;
#pragma unroll
    for (int v = 0; v < 5; v++) {
      float4 w4 = *(const float4*)(PW + ((size_t)(v * 1024 + c)) * 4);
      float val = pat[v * 4 + 0] * w4.x + pat[v * 4 + 1] * w4.y
                + pat[v * 4 + 2] * w4.z + pat[v * 4 + 3] * w4.w
                + CV[v * 1024 + c];
      acc += am[h * 5 + v] * val;
    }
    agg[(size_t)m * 1024 + c] = acc;
  }
}

// ---------------------------------------------------------------------------
// Generic fp32 GEMM (kept for agg-out EPI3 and hf N=20):
// C[M][N] = A[M][K] @ W[N][K]^T + bias. EPI: 0 plain, 1 gelu, 2 +resid, 3 +pos
// ---------------------------------------------------------------------------
template <int EPI>
__global__ __launch_bounds__(256) void k_gemm(
    const float* __restrict__ A, const float* __restrict__ W,
    const float* __restrict__ bias, float* __restrict__ C,
    int M, int N, int K,
    const float* __restrict__ resid,
    const float* __restrict__ pos, const float* __restrict__ ltw,
    const float* __restrict__ ltb, const float* __restrict__ lead) {
  __shared__ float As[16][68];
  __shared__ float Ws[16][68];
  int m0 = blockIdx.y * 64, n0 = blockIdx.x * 64;
  int tid = threadIdx.x;
  int tx = tid & 15, ty = tid >> 4;
  int lr = tid & 63, lk = (tid >> 6) * 4;
  float acc[4][4] = {};
  for (int k0 = 0; k0 < K; k0 += 16) {
    float4 av = *(const float4*)(A + (size_t)(m0 + lr) * K + k0 + lk);
    float4 wv = {0.f, 0.f, 0.f, 0.f};
    if (n0 + lr < N) {
      wv = *(const float4*)(W + (size_t)(n0 + lr) * K + k0 + lk);
    }
    __syncthreads();
    As[lk + 0][lr] = av.x; As[lk + 1][lr] = av.y;
    As[lk + 2][lr] = av.z; As[lk + 3][lr] = av.w;
    Ws[lk + 0][lr] = wv.x; Ws[lk + 1][lr] = wv.y;
    Ws[lk + 2][lr] = wv.z; Ws[lk + 3][lr] = wv.w;
    __syncthreads();
#pragma unroll
    for (int kk = 0; kk < 16; kk++) {
      float4 a = *(const float4*)&As[kk][ty * 4];
      float4 b = *(const float4*)&Ws[kk][tx * 4];
      acc[0][0] += a.x * b.x; acc[0][1] += a.x * b.y; acc[0][2] += a.x * b.z; acc[0][3] += a.x * b.w;
      acc[1][0] += a.y * b.x; acc[1][1] += a.y * b.y; acc[1][2] += a.y * b.z; acc[1][3] += a.y * b.w;
      acc[2][0] += a.z * b.x; acc[2][1] += a.z * b.y; acc[2][2] += a.z * b.z; acc[2][3] += a.z * b.w;
      acc[3][0] += a.w * b.x; acc[3][1] += a.w * b.y; acc[3][2] += a.w * b.z; acc[3][3] += a.w * b.w;
    }
  }
#pragma unroll
  for (int ii = 0; ii < 4; ii++) {
    int m = m0 + ty * 4 + ii;
#pragma unroll
    for (int jj = 0; jj < 4; jj++) {
      int n = n0 + tx * 4 + jj;
      if (n >= N) continue;
      float v = acc[ii][jj] + bias[n];
      if (EPI == 1) v = 0.5f * v * (1.f + erff(v * 0.70710678118f));
      if (EPI == 2) v += resid[(size_t)m * N + n];
      if (EPI == 3) {
        int b = m >> 9, l = m & 511;
        v += pos[(size_t)l * 1024 + n] + ltw[n] * lead[b] + ltb[n];
      }
      C[(size_t)m * N + n] = v;
    }
  }
}

// ---------------------------------------------------------------------------
// LayerNorm over D=1024 (grid M). In-place safe.
// ---------------------------------------------------------------------------
__global__ __launch_bounds__(256) void k_ln(
    const float* __restrict__ src, const float* __restrict__ add,
    const float* __restrict__ g, const float* __restrict__ bb,
    float* __restrict__ dst) {
  __shared__ float red[8];
  int m = blockIdx.x, tid = threadIdx.x;
  float4 x = *(const float4*)(src + (size_t)m * 1024 + tid * 4);
  if (add) {
    float4 a2 = *(const float4*)(add + (size_t)m * 1024 + tid * 4);
    x.x += a2.x; x.y += a2.y; x.z += a2.z; x.w += a2.w;
  }
  float s1 = x.x + x.y + x.z + x.w;
  float s2 = x.x * x.x + x.y * x.y + x.z * x.z + x.w * x.w;
  for (int off = 1; off < 64; off <<= 1) {
    s1 += __shfl_xor(s1, off); s2 += __shfl_xor(s2, off);
  }
  if ((tid & 63) == 0) { red[(tid >> 6) * 2] = s1; red[(tid >> 6) * 2 + 1] = s2; }
  __syncthreads();
  s1 = red[0] + red[2] + red[4] + red[6];
  s2 = red[1] + red[3] + red[5] + red[7];
  float mean = s1 * (1.f / 1024.f);
  float var = s2 * (1.f / 1024.f) - mean * mean;
  float rstd = rsqrtf(var + EPSF);
  int c = tid * 4;
  float4 o;
  o.x = (x.x - mean) * rstd * g[c + 0] + bb[c + 0];
  o.y = (x.y - mean) * rstd * g[c + 1] + bb[c + 1];
  o.z = (x.z - mean) * rstd * g[c + 2] + bb[c + 2];
  o.w = (x.w - mean) * rstd * g[c + 3] + bb[c + 3];
  *(float4*)(dst + (size_t)m * 1024 + c) = o;
}

// ---------------------------------------------------------------------------
// Patch attention: per (b,h,ntile16). Two-pass softmax with S in LDS.
// ---------------------------------------------------------------------------
__global__ __launch_bounds__(256) void k_attn(
    const float* __restrict__ qkv, float* __restrict__ o) {
  __shared__ float Q[16][68];
  __shared__ float S[16][516];
  __shared__ float KV[32][68];
  int bid = blockIdx.x;
  int nt = bid & 31, h = (bid >> 5) & 15, b = bid >> 9;
  int tid = threadIdx.x;
  for (int i = tid; i < 16 * 64; i += 256) {
    int r = i >> 6, e = i & 63;
    Q[r][e] = qkv[(size_t)(b * 512 + nt * 16 + r) * 3072 + h * 64 + e];
  }
  __syncthreads();
  int r = tid >> 4, lane = tid & 15;
  for (int kt = 0; kt < 16; kt++) {
    for (int i = tid; i < 32 * 64; i += 256) {
      int rr = i >> 6, e = i & 63;
      KV[rr][e] = qkv[(size_t)(b * 512 + kt * 32 + rr) * 3072 + 1024 + h * 64 + e];
    }
    __syncthreads();
    for (int jj = lane; jj < 32; jj += 16) {
      float acc = 0.f;
#pragma unroll 8
      for (int e = 0; e < 64; e++) acc += Q[r][e] * KV[jj][e];
      S[r][kt * 32 + jj] = acc * 0.125f;
    }
    __syncthreads();
  }
  float mx = -1e30f;
  for (int j = lane; j < 512; j += 16) mx = fmaxf(mx, S[r][j]);
  for (int off = 1; off < 16; off <<= 1) mx = fmaxf(mx, __shfl_xor(mx, off));
  float sum = 0.f;
  for (int j = lane; j < 512; j += 16) {
    float e = __expf(S[r][j] - mx);
    S[r][j] = e; sum += e;
  }
  sum = red16(sum);
  float inv = 1.f / sum;
  int e0 = lane * 4;
  float4 accv = {0.f, 0.f, 0.f, 0.f};
  for (int kt = 0; kt < 16; kt++) {
    __syncthreads();
    for (int i = tid; i < 32 * 64; i += 256) {
      int rr = i >> 6, e = i & 63;
      KV[rr][e] = qkv[(size_t)(b * 512 + kt * 32 + rr) * 3072 + 2048 + h * 64 + e];
    }
    __syncthreads();
#pragma unroll 8
    for (int j = 0; j < 32; j++) {
      float p = S[r][kt * 32 + j] * inv;
      accv.x += p * KV[j][e0 + 0]; accv.y += p * KV[j][e0 + 1];
      accv.z += p * KV[j][e0 + 2]; accv.w += p * KV[j][e0 + 3];
    }
  }
  float* op = o + (size_t)(b * 512 + nt * 16 + r) * 1024 + h * 64 + e0;
  op[0] = accv.x; op[1] = accv.y; op[2] = accv.z; op[3] = accv.w;
}

// ---------------------------------------------------------------------------
// swz/swz8: bf16 LDS tile layout (v7/v9-verified), per 16-token group.
// ---------------------------------------------------------------------------
__device__ __forceinline__ int swz(int m, int c) {
  int g = c >> 3;
  g = (g & ~7) | ((g ^ m) & 7);
  return m * 1024 + g * 8 + (c & 7);
}
__device__ __forceinline__ int swz8(int m, int k) {  // k multiple of 8
  int g = k >> 3;
  g = (g & ~7) | ((g ^ m) & 7);
  return m * 1024 + g * 8;
}

// ---------------------------------------------------------------------------
// MFMA GEMM for f32 activations: C[1024][N] = A[1024][1024] @ Wblob^T + bias.
// Grid = (N/256 slices)*64 groups, bid = cs*64+g. 16 waves; wave wv stages
// token-row wv (f32->bf16->swz LDS) then computes col-tile ct=cs*16+wv.
// EPI: 0 plain, 1 gelu(exact), 2 +resid.
// ---------------------------------------------------------------------------
template <int EPI>
__global__ __launch_bounds__(1024) void k_mg(
    const float* __restrict__ A, const u16* __restrict__ blob,
    const float* __restrict__ bias, float* __restrict__ C, int N,
    const float* __restrict__ resid) {
  __shared__ __align__(16) u16 bufA[16 * 1024];
  int tid = threadIdx.x;
  int bid = blockIdx.x;
  int cs = bid >> 6, g = bid & 63;
  int wv = tid >> 6, lane = tid & 63;
  int row16 = lane & 15, quad = lane >> 4;
  // ---- stage A rows: wave wv loads token g*16+wv, lane cols [lane*16,+16) ----
  {
    const float* ar = A + (size_t)(g * 16 + wv) * 1024 + lane * 16;
#pragma unroll
    for (int q = 0; q < 4; q++) {
      float4 v = *(const float4*)(ar + q * 4);
      int c = lane * 16 + q * 4;
      bufA[swz(wv, c + 0)] = f2b(v.x); bufA[swz(wv, c + 1)] = f2b(v.y);
      bufA[swz(wv, c + 2)] = f2b(v.z); bufA[swz(wv, c + 3)] = f2b(v.w);
    }
  }
  __syncthreads();
  int ct = cs * 16 + wv;
  int n = cs * 256 + wv * 16 + row16;
  const u16* wb = blob + ((size_t)ct * 2048 + lane) * 8;
  f32x4 acc = {0.f, 0.f, 0.f, 0.f};
#pragma unroll
  for (int kk = 0; kk < 32; kk++) {
    bf16x8 wf = *(const bf16x8*)(wb + kk * 512);
    bf16x8 aF = *(const bf16x8*)(bufA + swz8(row16, kk * 32 + quad * 8));
    acc = __builtin_amdgcn_mfma_f32_16x16x32_bf16(aF, wf, acc, 0, 0, 0);
  }
  float bv = bias[n];
#pragma unroll
  for (int r = 0; r < 4; r++) {
    int tok = g * 16 + quad * 4 + r;
    float v = acc[r] + bv;
    if (EPI == 1) v = 0.5f * v * (1.f + erff(v * 0.70710678118f));
    if (EPI == 2) v += resid[(size_t)tok * 1024 + n];
    C[(size_t)tok * N + n] = v;
  }
}

// ---------------------------------------------------------------------------
// ODE kernels: fence-free kernel-per-phase (v13-verified structure).
// v15: k_og batches 4 token-groups per block (G4).
// Grid 256: bid -> gp = bid>>4 (0..15), cs = bid&15 (0..15).
// Wave wv: group g = gp*4+(wv>>2), col-tile ct = cs*4+(wv&3) (cols cs*64..+64).
// LDS: 4 act images (128KB). Weights: 4 unique ct x 32KB = 128KB/block,
// each frag read by 4 waves (L1-served).
// PASS 1: h_img[swz] = bf16(relu(src@w1^T + b1))
// PASS 2: zraw[token][col] = f32(src@w2^T)
// ---------------------------------------------------------------------------
template <int PASS>
__global__ __launch_bounds__(1024) void k_og(
    const u16* __restrict__ wp, const float* __restrict__ bias,
    const u16* __restrict__ src_img, u16* __restrict__ h_img,
    float* __restrict__ zraw) {
  __shared__ __align__(16) u16 bufA[4 * 16 * 1024];  // 128KB: 4 group images
  int tid = threadIdx.x;
  int bid = blockIdx.x;
  int gp = bid >> 4, cs = bid & 15;
  int wvid = tid >> 6, lane = tid & 63;
  int row16 = lane & 15, quad = lane >> 4;
  int gl = wvid >> 2;            // group-local 0..3
  int g = gp * 4 + gl;           // token group
  int ct = cs * 4 + (wvid & 3);  // global col-tile 0..63
  int n = ct * 16 + row16;       // this lane's output column
  const u16* wb = wp + ((size_t)ct * 2048 + lane) * 8;  // packed frag base
  // ---- stage 4 act images: wave wv stages quarter q=(wv&3) of group gl ----
  {
    int q = wvid & 3;
    const u16* src = src_img + (size_t)g * 16384 + q * 4096 + lane * 8;
    u16* dst = bufA + gl * 16384 + q * 4096;
#pragma unroll
    for (int i = 0; i < 8; i++) {
      __builtin_amdgcn_global_load_lds(
          (const __attribute__((address_space(1))) uint32_t*)(src + i * 512),
          (__attribute__((address_space(3))) uint32_t*)(dst + i * 512), 16, 0, 0);
    }
  }
  VMCNT(0);
  __syncthreads();
  // ---- MFMA K-loop (v9-verified fragment path, group-local image) ----
  const u16* bA = bufA + gl * 16384;
  f32x4 acc = {0.f, 0.f, 0.f, 0.f};
#pragma unroll
  for (int kk = 0; kk < 32; kk++) {
    bf16x8 wf = *(const bf16x8*)(wb + kk * 512);
    bf16x8 aF = *(const bf16x8*)(bA + swz8(row16, kk * 32 + quad * 8));
    acc = __builtin_amdgcn_mfma_f32_16x16x32_bf16(aF, wf, acc, 0, 0, 0);
  }
  if (PASS == 1) {
    float bv = bias[n];
#pragma unroll
    for (int r = 0; r < 4; r++) {
      int ml = quad * 4 + r;
      h_img[(size_t)g * 16384 + swz(ml, n)] = f2b(fmaxf(acc[r] + bv, 0.f));
    }
  } else {
#pragma unroll
    for (int r = 0; r < 4; r++) {
      int tok = g * 16 + quad * 4 + r;
      zraw[(size_t)tok * 1024 + n] = acc[r];
    }
  }
}

// Init: y = nvf = xs; act image = bf16(xs); out = xs. Grid 1024 (token/block).
__global__ __launch_bounds__(256) void k_odeinit(
    const float* __restrict__ xs, float* __restrict__ y,
    float* __restrict__ nvf, u16* __restrict__ act_img,
    float* __restrict__ out) {
  int t = blockIdx.x, tid = threadIdx.x;
  int c = tid * 4;
  int g = t >> 4, ml = t & 15;
  float4 v = *(const float4*)(xs + (size_t)t * 1024 + c);
  *(float4*)(y + (size_t)t * 1024 + c) = v;
  *(float4*)(nvf + (size_t)t * 1024 + c) = v;
  *(float4*)(out + (size_t)t * 1024 + c) = v;
  u16* ag = act_img + (size_t)g * 16384;
  ag[swz(ml, c + 0)] = f2b(v.x); ag[swz(ml, c + 1)] = f2b(v.y);
  ag[swz(ml, c + 2)] = f2b(v.z); ag[swz(ml, c + 3)] = f2b(v.w);
}

// RK4 + LN epilogue. Grid 1024 (token/block), 256 thr.
__global__ __launch_bounds__(256) void k_rk4(
    const float* __restrict__ zraw, const float* __restrict__ b2,
    const float* __restrict__ ng, const float* __restrict__ nb,
    float* __restrict__ y, float* __restrict__ accr,
    float* __restrict__ nvf, u16* __restrict__ act_img,
    float* __restrict__ out, const float* __restrict__ lead,
    int s, int ph) {
  __shared__ float red[8];
  int t = blockIdx.x, tid = threadIdx.x;
  int c = tid * 4;
  int g = t >> 4, ml = t & 15;
  float4 zr = *(const float4*)(zraw + (size_t)t * 1024 + c);
  float4 bb = *(const float4*)(b2 + c);
  float4 nv = *(const float4*)(nvf + (size_t)t * 1024 + c);
  float z0 = zr.x + bb.x + nv.x, z1 = zr.y + bb.y + nv.y;
  float z2 = zr.z + bb.z + nv.z, z3 = zr.w + bb.w + nv.w;
  float s1 = z0 + z1 + z2 + z3;
  float s2 = z0 * z0 + z1 * z1 + z2 * z2 + z3 * z3;
  for (int off = 1; off < 64; off <<= 1) {
    s1 += __shfl_xor(s1, off); s2 += __shfl_xor(s2, off);
  }
  if ((tid & 63) == 0) { red[(tid >> 6) * 2] = s1; red[(tid >> 6) * 2 + 1] = s2; }
  __syncthreads();
  s1 = red[0] + red[2] + red[4] + red[6];
  s2 = red[1] + red[3] + red[5] + red[7];
  float mean = s1 * (1.f / 1024.f);
  float var = s2 * (1.f / 1024.f) - mean * mean;
  float rstd = rsqrtf(var + EPSF);
  float4 gv = *(const float4*)(ng + c);
  float4 bv = *(const float4*)(nb + c);
  float k0 = (z0 - mean) * rstd * gv.x + bv.x;
  float k1 = (z1 - mean) * rstd * gv.y + bv.y;
  float k2 = (z2 - mean) * rstd * gv.z + bv.z;
  float k3 = (z3 - mean) * rstd * gv.w + bv.w;
  float4 yv = *(const float4*)(y + (size_t)t * 1024 + c);
  float4 ac;
  float cf = (ph < 2) ? 0.5f * RESF : RESF;
  const float h6 = RESF / 6.0f;
  float4 nn;
  if (ph == 0) {
    ac.x = k0; ac.y = k1; ac.z = k2; ac.w = k3;
    nn.x = yv.x + cf * k0; nn.y = yv.y + cf * k1;
    nn.z = yv.z + cf * k2; nn.w = yv.w + cf * k3;
    *(float4*)(accr + (size_t)t * 1024 + c) = ac;
  } else if (ph < 3) {
    ac = *(const float4*)(accr + (size_t)t * 1024 + c);
    ac.x += 2.f * k0; ac.y += 2.f * k1; ac.z += 2.f * k2; ac.w += 2.f * k3;
    nn.x = yv.x + cf * k0; nn.y = yv.y + cf * k1;
    nn.z = yv.z + cf * k2; nn.w = yv.w + cf * k3;
    *(float4*)(accr + (size_t)t * 1024 + c) = ac;
  } else {
    ac = *(const float4*)(accr + (size_t)t * 1024 + c);
    yv.x += h6 * (ac.x + k0); yv.y += h6 * (ac.y + k1);
    yv.z += h6 * (ac.z + k2); yv.w += h6 * (ac.w + k3);
    nn = yv;
    *(float4*)(y + (size_t)t * 1024 + c) = yv;
    int idxb = (int)roundf(lead[t >> 9] * 100.0f);
    if ((s + 1) == idxb)
      *(float4*)(out + (size_t)t * 1024 + c) = yv;
  }
  *(float4*)(nvf + (size_t)t * 1024 + c) = nn;
  u16* ag = act_img + (size_t)g * 16384;
  ag[swz(ml, c + 0)] = f2b(nn.x); ag[swz(ml, c + 1)] = f2b(nn.y);
  ag[swz(ml, c + 2)] = f2b(nn.z); ag[swz(ml, c + 3)] = f2b(nn.w);
}

// ---------------------------------------------------------------------------
// Unpatchify: y3[m][p*10+q*5+c] -> out[b][c][hh*2+p][ww*2+q], FLOAT32
// ---------------------------------------------------------------------------
__global__ __launch_bounds__(256) void k_unpatch(
    const float* __restrict__ y3, float* __restrict__ outp) {
  int o = blockIdx.x * 256 + threadIdx.x;
  if (o >= 20480) return;
  int b = o / 10240;
  int c = (o / 2048) % 5;
  int hrow = (o / 64) % 32;
  int wcol = o % 64;
  int hh = hrow >> 1, p = hrow & 1, ww = wcol >> 1, q = wcol & 1;
  int m2 = b * 512 + hh * 32 + ww;
  int colj = p * 10 + q * 5 + c;
  outp[o] = y3[(size_t)m2 * 20 + colj];
}

// ===========================================================================
extern "C" void kernel_launch(void* const* d_in, const int* in_sizes, int n_in,
                              void* d_out, int out_size, void* d_ws, size_t ws_size,
                              hipStream_t stream) {
  const float* x         = (const float*)d_in[0];
  const float* lead      = (const float*)d_in[1];
  const float* patch_w   = (const float*)d_in[2];
  const float* patch_b   = (const float*)d_in[3];
  const float* var_embed = (const float*)d_in[4];
  const float* var_query = (const float*)d_in[5];
  const float* agg_in_w  = (const float*)d_in[6];
  const float* agg_in_b  = (const float*)d_in[7];
  const float* agg_out_w = (const float*)d_in[8];
  const float* agg_out_b = (const float*)d_in[9];
  const float* pos_embed = (const float*)d_in[10];
  const float* lt_w      = (const float*)d_in[11];
  const float* lt_b      = (const float*)d_in[12];
  const float* blk_qkv_w = (const float*)d_in[13];
  const float* blk_qkv_b = (const float*)d_in[14];
  const float* blk_out_w = (const float*)d_in[15];
  const float* blk_out_b = (const float*)d_in[16];
  const float* blk_n1_g  = (const float*)d_in[17];
  const float* blk_n1_b  = (const float*)d_in[18];
  const float* blk_n2_g  = (const float*)d_in[19];
  const float* blk_n2_b  = (const float*)d_in[20];
  const float* ode_w1    = (const float*)d_in[21];
  const float* ode_b1    = (const float*)d_in[22];
  const float* ode_w2    = (const float*)d_in[23];
  const float* ode_b2    = (const float*)d_in[24];
  const float* ode_ng    = (const float*)d_in[25];
  const float* ode_nb    = (const float*)d_in[26];
  const float* norm_g    = (const float*)d_in[27];
  const float* norm_b    = (const float*)d_in[28];
  const float* h1_w      = (const float*)d_in[29];
  const float* h1_b      = (const float*)d_in[30];
  const float* h2_w      = (const float*)d_in[31];
  const float* h2_b      = (const float*)d_in[32];
  const float* hf_w      = (const float*)d_in[33];
  const float* hf_b      = (const float*)d_in[34];
  (void)in_sizes; (void)n_in; (void)out_size; (void)ws_size;

  float* ws = (float*)d_ws;
  // ODE buffers in ode-dead regions (qkv/attno/t1):
  u16*   act16 = (u16*)(ws + 0);        // 2MB act image
  u16*   h16   = (u16*)(ws + 524288);   // 2MB h image
  float* zraw  = ws + 1048576;          // 4MB raw GEMM2 out
  float* ybuf  = ws + 2097152;          // 4MB RK4 y      (end 3145728)
  float* accr  = ws + 3145728;          // 4MB RK4 accum  (attno region)
  float* nvf   = ws + 4194304;          // 4MB f32 act    (t1 region)
  float* patches = ws + 0;         // 20480 (stage-1 only; dead before ode)
  float* qvec    = ws + 20480;     // 1024
  float* qb      = ws + 21504;     // 256 (16 used)
  float* u       = ws + 21760;     // 16384
  float* PU      = ws + 38144;     // 320
  float* C0      = ws + 38464;     // 80 (pad to 40960)
  float* amat    = ws + 40960;     // 81920
  float* PW      = ws + 122880;    // 20480
  float* CV      = ws + 143360;    // 5120  (end 148480)
  float* agg     = ws + 3145728;   // 1048576 (attno slot; dead by then)
  float* qkv   = ws + 0;           // 3145728
  float* attno = ws + 3145728;     // 1048576
  float* t1    = ws + 4194304;     // 1048576
  float* odeo  = ws + 5242880;     // 1048576
  float* xs    = ws + 6291456;     // 1048576
  u16*   w16a  = (u16*)(ws + 7340032);  // packed ode w1 (bf16 frag blob)
  u16*   w16b  = (u16*)(ws + 7864320);  // packed ode w2
  // transient GEMM weight blobs (lifetimes verified against region uses):
  u16*   qkvblob = (u16*)(ws + 3145728); // 6MB in attno+t1 (dead until attn)
  u16*   aoblob  = (u16*)(ws + 5242880); // 2MB in odeo (dead until ODE init)
  u16*   hblob   = (u16*)(ws + 3145728); // 2MB in attno region (head only)
  float* y1 = ws + 0;
  float* y2 = ws + 1048576;
  float* y3 = ws + 2097152;        // 20480

  // ---- stage 1 ----
  k_patches<<<dim3(80), dim3(256), 0, stream>>>(x, patches);
  k_qvec<<<dim3(64), dim3(256), 0, stream>>>(var_query, agg_in_w, agg_in_b, qvec);
  k_qb<<<dim3(1), dim3(256), 0, stream>>>(qvec, agg_in_b + 1024, qb);
  k_u<<<dim3(64), dim3(256), 0, stream>>>(qvec, agg_in_w + (size_t)1024 * 1024, u);
  k_pu<<<dim3(80), dim3(256), 0, stream>>>(patch_w, patch_b, var_embed, u, qb, PU, C0);
  k_pw<<<dim3(5120), dim3(256), 0, stream>>>(
      agg_in_w + (size_t)2048 * 1024, agg_in_b + 2048, patch_w, patch_b,
      var_embed, PW, CV);
  k_scoresm<<<dim3(1024), dim3(256), 0, stream>>>(patches, PU, C0, amat);
  k_agg<<<dim3(1024), dim3(256), 0, stream>>>(patches, PW, CV, amat, agg);
  k_gemm<3><<<dim3(16, 16), dim3(256), 0, stream>>>(
      agg, agg_out_w, agg_out_b, xs, 1024, 1024, 1024,
      nullptr, pos_embed, lt_w, lt_b, lead);

  // ---- transformer blocks ----
  for (int i = 0; i < 2; i++) {
    // qkv = xs @ Wqkv^T + b  (bf16 MFMA; blob in attno+t1, dead until attn)
    k_pack<<<dim3(12288), dim3(256), 0, stream>>>(
        blk_qkv_w + (size_t)i * 3072 * 1024, qkvblob);
    k_mg<0><<<dim3(768), dim3(1024), 0, stream>>>(
        xs, qkvblob, blk_qkv_b + i * 3072, qkv, 3072, nullptr);
    k_attn<<<dim3(1024), dim3(256), 0, stream>>>(qkv, attno);
    // t1 = attno @ Wout^T + b + xs  (bf16 MFMA; blob in odeo region)
    k_pack<<<dim3(4096), dim3(256), 0, stream>>>(
        blk_out_w + (size_t)i * 1048576, aoblob);
    k_mg<2><<<dim3(256), dim3(1024), 0, stream>>>(
        attno, aoblob, blk_out_b + i * 1024, t1, 1024, xs);
    k_ln<<<dim3(1024), dim3(256), 0, stream>>>(
        t1, (const float*)nullptr, blk_n1_g + i * 1024, blk_n1_b + i * 1024, xs);
    k_pack<<<dim3(4096), dim3(256), 0, stream>>>(
        ode_w1 + (size_t)i * 1048576, w16a);
    k_pack<<<dim3(4096), dim3(256), 0, stream>>>(
        ode_w2 + (size_t)i * 1048576, w16b);
    // ---- fence-free ODE: 3 kernels per RK4 phase (v13 structure, G4 og) ----
    k_odeinit<<<dim3(1024), dim3(256), 0, stream>>>(xs, ybuf, nvf, act16, odeo);
    for (int s = 0; s < NSTEPS; s++) {
      for (int ph = 0; ph < 4; ph++) {
        k_og<1><<<dim3(256), dim3(1024), 0, stream>>>(
            w16a, ode_b1 + i * 1024, act16, h16, nullptr);
        k_og<2><<<dim3(256), dim3(1024), 0, stream>>>(
            w16b, nullptr, h16, nullptr, zraw);
        k_rk4<<<dim3(1024), dim3(256), 0, stream>>>(
            zraw, ode_b2 + i * 1024, ode_ng + i * 1024, ode_nb + i * 1024,
            ybuf, accr, nvf, act16, odeo, lead, s, ph);
      }
    }
    k_ln<<<dim3(1024), dim3(256), 0, stream>>>(
        xs, odeo, blk_n2_g + i * 1024, blk_n2_b + i * 1024, xs);
  }

  // ---- head ----
  k_ln<<<dim3(1024), dim3(256), 0, stream>>>(
      xs, (const float*)nullptr, norm_g, norm_b, xs);
  k_pack<<<dim3(4096), dim3(256), 0, stream>>>(h1_w, hblob);
  k_mg<1><<<dim3(256), dim3(1024), 0, stream>>>(
      xs, hblob, h1_b, y1, 1024, nullptr);
  k_pack<<<dim3(4096), dim3(256), 0, stream>>>(h2_w, hblob);
  k_mg<1><<<dim3(256), dim3(1024), 0, stream>>>(
      y1, hblob, h2_b, y2, 1024, nullptr);
  k_gemm<0><<<dim3(1, 16), dim3(256), 0, stream>>>(
      y2, hf_w, hf_b, y3, 1024, 20, 1024, nullptr, nullptr, nullptr, nullptr, nullptr);
  k_unpatch<<<dim3(80), dim3(256), 0, stream>>>(y3, (float*)d_out);
}

// Round 18
// 2715.396 us; speedup vs baseline: 1.0445x; 1.0445x over previous
//
#include <hip/hip_runtime.h>
#include <stdint.h>

// ============================================================================
// ConViTCast: B=2 V=5 H=32 W=64 P=2 D=1024 NH=16 hd=64 DEPTH=2 L=512 BL=1024
// R13 this session: v16 — v14 k_og (G4 REVERTED) + nvf elimination.
// R13 evidence (v15): G4 token-batching 2836us vs v14 2763us — bit-identical
// (absmax 0.001953125) but no win -> per-CU L2 weight traffic was NOT the
// k_og bottleneck. Phase ~24us = ~half launch/dependency overhead (3 dep
// launches x ~2us) + k_og ~4-5us x2 + k_rk4 ~6us.
// v16: revert k_og to v14's verified form; drop the nvf f32 activation copy
// (8MB/phase of k_rk4's ~28MB): residual read as bf16 from the swizzled act
// image (z = zraw + b2 + b2f(act)) — the v7-v12 verified arithmetic
// (absmax 9.77e-4 lineage). k_rk4 ~6 -> ~4.3us.
// Predict: total ~2600-2680us; absmax <= 0.00195. If flat: phase is
// launch-bound -> attack kernel count / MFMA attention next.
// [R14-R17: identical resubmits — GPUAcquisitionTimeout x4 (env-side; fires
//  pre-compilation, content-independent). Audits (4 passes) confirmed
//  read/write ordering, 8B alignment, arithmetic lineage, workspace
//  lifetimes. Fallback anchor: v14 @ 2763us. Phase-fusion queued.]
// ============================================================================

#define NSTEPS 10
#define RESF 0.01f
#define EPSF 1e-5f

typedef unsigned short u16;
typedef unsigned int u32;
typedef __attribute__((ext_vector_type(8))) short bf16x8;
typedef __attribute__((ext_vector_type(4))) float f32x4;

// s_waitcnt vmcnt(N), ignore exp/lgkm (gfx9 encoding: vm[3:0]|[15:14], exp=7, lgkm=15)
#define VMCNT(N) __builtin_amdgcn_s_waitcnt(0x0F70 | ((N) & 0xF) | ((((N) >> 4) & 0x3) << 14))

__device__ __forceinline__ float b2f(u16 u) {
  return __uint_as_float(((uint32_t)u) << 16);
}
__device__ __forceinline__ u16 f2b(float f) {
  uint32_t x = __float_as_uint(f);
  uint32_t r = x + 0x7fffu + ((x >> 16) & 1u);  // round-to-nearest-even
  return (u16)(r >> 16);
}
__device__ __forceinline__ float red16(float v) {
  v += __shfl_xor(v, 1); v += __shfl_xor(v, 2);
  v += __shfl_xor(v, 4); v += __shfl_xor(v, 8);
  return v;
}

// Repack f32 weight [Ncols][1024 k] -> bf16 MFMA-frag blob (grid = N*4 blocks):
// blob[((ct*32+kk)*64+l)*8+j] = w[ct*16+(l&15)][kk*32+(l>>4)*8+j]
__global__ __launch_bounds__(256) void k_pack(
    const float* __restrict__ in, u16* __restrict__ out16) {
  int i = blockIdx.x * 256 + threadIdx.x;
  int j = i & 7;
  int l = (i >> 3) & 63;
  int kk = (i >> 9) & 31;
  int ct = i >> 14;
  int col = ct * 16 + (l & 15);
  int k = kk * 32 + ((l >> 4) << 3) + j;
  out16[i] = f2b(in[(size_t)col * 1024 + k]);
}

// ---------------------------------------------------------------------------
// Extract patches[m*20 + v*4 + p] from x[b,v,h,w]; m=b*512+l, l=hh*32+ww
// ---------------------------------------------------------------------------
__global__ __launch_bounds__(256) void k_patches(
    const float* __restrict__ x, float* __restrict__ patches) {
  int i = blockIdx.x * 256 + threadIdx.x;  // grid 80*256 = 20480
  int m = i / 20, r = i % 20;
  int v = r >> 2, p = r & 3;
  int b = m >> 9, l = m & 511;
  int hh = l >> 5, ww = l & 31;
  int pr = p >> 1, pc = p & 1;
  patches[i] = x[((size_t)(b * 5 + v) * 32 + hh * 2 + pr) * 64 + ww * 2 + pc];
}

// qvec = var_query @ Wq^T + bq   (grid 64)
__global__ __launch_bounds__(256) void k_qvec(
    const float* __restrict__ vq, const float* __restrict__ w,
    const float* __restrict__ bias, float* __restrict__ qvec) {
  int dq = blockIdx.x * 16 + (threadIdx.x >> 4);
  int lane = threadIdx.x & 15;
  float p = 0.f;
  for (int j = 0; j < 64; j++) {
    int d = lane + 16 * j;
    p += vq[d] * w[(size_t)dq * 1024 + d];
  }
  p = red16(p);
  if (lane == 0) qvec[dq] = p + bias[dq];
}

// qb[h] = sum_e qvec[h*64+e]*bk[h*64+e]   (grid 1)
__global__ __launch_bounds__(256) void k_qb(
    const float* __restrict__ qvec, const float* __restrict__ bk,
    float* __restrict__ qb) {
  int h = threadIdx.x >> 4, lane = threadIdx.x & 15;
  float p = 0.f;
  for (int e = lane; e < 64; e += 16) p += qvec[h * 64 + e] * bk[h * 64 + e];
  p = red16(p);
  if (lane == 0) qb[h] = p;
}

// u[h][d] = sum_e qvec[h*64+e] * Wk[h*64+e][d]   (grid 64)
__global__ __launch_bounds__(256) void k_u(
    const float* __restrict__ qvec, const float* __restrict__ wk,
    float* __restrict__ u) {
  int d = blockIdx.x * 16 + (threadIdx.x & 15);
  int h = threadIdx.x >> 4;
  float acc = 0.f;
  for (int e = 0; e < 64; e++)
    acc += qvec[h * 64 + e] * wk[(size_t)(h * 64 + e) * 1024 + d];
  u[h * 1024 + d] = acc;
}

// PU[(v*16+h)*4+p] = 0.125*sum_d pw[v,d,p]*u[h,d]
// C0[v*16+h]       = 0.125*(sum_d (pb+ve)[v,d]*u[h,d] + qb[h])     (grid 80)
__global__ __launch_bounds__(256) void k_pu(
    const float* __restrict__ pw, const float* __restrict__ pb,
    const float* __restrict__ ve, const float* __restrict__ u,
    const float* __restrict__ qb, float* __restrict__ PU,
    float* __restrict__ C0) {
  int v = blockIdx.x / 16, h = blockIdx.x % 16;
  int t = threadIdx.x;
  float a0 = 0, a1 = 0, a2 = 0, a3 = 0, ac = 0;
  for (int d = t; d < 1024; d += 256) {
    float uu = u[h * 1024 + d];
    const float* p4 = pw + ((size_t)v * 1024 + d) * 4;
    a0 += p4[0] * uu; a1 += p4[1] * uu; a2 += p4[2] * uu; a3 += p4[3] * uu;
    ac += (pb[v * 1024 + d] + ve[v * 1024 + d]) * uu;
  }
  for (int off = 1; off < 64; off <<= 1) {
    a0 += __shfl_xor(a0, off); a1 += __shfl_xor(a1, off);
    a2 += __shfl_xor(a2, off); a3 += __shfl_xor(a3, off);
    ac += __shfl_xor(ac, off);
  }
  __shared__ float r[4][5];
  if ((t & 63) == 0) {
    int w = t >> 6;
    r[w][0] = a0; r[w][1] = a1; r[w][2] = a2; r[w][3] = a3; r[w][4] = ac;
  }
  __syncthreads();
  if (t == 0) {
    float s[5];
    for (int j = 0; j < 5; j++) s[j] = r[0][j] + r[1][j] + r[2][j] + r[3][j];
    float* pu = PU + (v * 16 + h) * 4;
    pu[0] = 0.125f * s[0]; pu[1] = 0.125f * s[1];
    pu[2] = 0.125f * s[2]; pu[3] = 0.125f * s[3];
    C0[v * 16 + h] = 0.125f * (s[4] + qb[h]);
  }
}

// PW[(v*1024+col)*4+p] = sum_d Wv[col,d]*pw[v,d,p]
// CV[v*1024+col]       = sum_d Wv[col,d]*(pb+ve)[v,d] + bv[col]    (grid 5120)
__global__ __launch_bounds__(256) void k_pw(
    const float* __restrict__ wv, const float* __restrict__ bv,
    const float* __restrict__ pw, const float* __restrict__ pb,
    const float* __restrict__ ve, float* __restrict__ PW,
    float* __restrict__ CV) {
  int v = blockIdx.x >> 10, col = blockIdx.x & 1023;
  int t = threadIdx.x;
  const float* wr = wv + (size_t)col * 1024;
  float4 w4 = *(const float4*)(wr + t * 4);
  float a0 = 0, a1 = 0, a2 = 0, a3 = 0, ac = 0;
#pragma unroll
  for (int j = 0; j < 4; j++) {
    int d = t * 4 + j;
    float wj = (j == 0) ? w4.x : (j == 1) ? w4.y : (j == 2) ? w4.z : w4.w;
    const float* p4 = pw + ((size_t)v * 1024 + d) * 4;
    a0 += wj * p4[0]; a1 += wj * p4[1]; a2 += wj * p4[2]; a3 += wj * p4[3];
    ac += wj * (pb[v * 1024 + d] + ve[v * 1024 + d]);
  }
  for (int off = 1; off < 64; off <<= 1) {
    a0 += __shfl_xor(a0, off); a1 += __shfl_xor(a1, off);
    a2 += __shfl_xor(a2, off); a3 += __shfl_xor(a3, off);
    ac += __shfl_xor(ac, off);
  }
  __shared__ float r[4][5];
  if ((t & 63) == 0) {
    int w = t >> 6;
    r[w][0] = a0; r[w][1] = a1; r[w][2] = a2; r[w][3] = a3; r[w][4] = ac;
  }
  __syncthreads();
  if (t == 0) {
    float s[5];
    for (int j = 0; j < 5; j++) s[j] = r[0][j] + r[1][j] + r[2][j] + r[3][j];
    float* o = PW + ((size_t)(v * 1024 + col)) * 4;
    o[0] = s[0]; o[1] = s[1]; o[2] = s[2]; o[3] = s[3];
    CV[v * 1024 + col] = s[4] + bv[col];
  }
}

// scores s[v][h] = patches[m,v]·PU[v,h] + C0[v,h]; softmax over v
// -> amat[m*80 + h*5 + v]                                          (grid 1024)
__global__ __launch_bounds__(256) void k_scoresm(
    const float* __restrict__ patches, const float* __restrict__ PU,
    const float* __restrict__ C0, float* __restrict__ amat) {
  __shared__ float pat[20];
  __shared__ float sa[16][8];
  int m = blockIdx.x, t = threadIdx.x;
  if (t < 20) pat[t] = patches[m * 20 + t];
  __syncthreads();
  if (t < 80) {
    int v = t / 16, h = t % 16;
    const float* pu = PU + (v * 16 + h) * 4;
    float s = C0[v * 16 + h] + pat[v * 4 + 0] * pu[0] + pat[v * 4 + 1] * pu[1]
            + pat[v * 4 + 2] * pu[2] + pat[v * 4 + 3] * pu[3];
    sa[h][v] = s;
  }
  __syncthreads();
  if (t < 16) {
    float mx = sa[t][0];
    for (int v = 1; v < 5; v++) mx = fmaxf(mx, sa[t][v]);
    float e[5], sum = 0.f;
    for (int v = 0; v < 5; v++) { e[v] = __expf(sa[t][v] - mx); sum += e[v]; }
    float inv = 1.f / sum;
    for (int v = 0; v < 5; v++) amat[m * 80 + t * 5 + v] = e[v] * inv;
  }
}

// agg[m,c] = sum_v amat[m,h(c),v] * (patches[m,v]·PW[v,c] + CV[v,c]) (grid 1024)
__global__ __launch_bounds__(256) void k_agg(
    const float* __restrict__ patches, const float* __restrict__ PW,
    const float* __restrict__ CV, const float* __restrict__ amat,
    float* __restrict__ agg) {
  __shared__ float pat[20];
  __shared__ float am[80];
  int m = blockIdx.x, t = threadIdx.x;
  if (t < 20) pat[t] = patches[m * 20 + t];
  if (t < 80) am[t] = amat[m * 80 + t];
  __syncthreads();
  int c0 = t * 4;
#pragma unroll
  for (int j = 0; j < 4; j++) {
    int c = c0 + j;
    int h = c >> 6;
    float acc = 0.f;
#pragma unroll
    for (int v = 0; v < 5; v++) {
      float4 w4 = *(const float4*)(PW + ((size_t)(v * 1024 + c)) * 4);
      float val = pat[v * 4 + 0] * w4.x + pat[v * 4 + 1] * w4.y
                + pat[v * 4 + 2] * w4.z + pat[v * 4 + 3] * w4.w
                + CV[v * 1024 + c];
      acc += am[h * 5 + v] * val;
    }
    agg[(size_t)m * 1024 + c] = acc;
  }
}

// ---------------------------------------------------------------------------
// Generic fp32 GEMM (kept for agg-out EPI3 and hf N=20):
// C[M][N] = A[M][K] @ W[N][K]^T + bias. EPI: 0 plain, 1 gelu, 2 +resid, 3 +pos
// ---------------------------------------------------------------------------
template <int EPI>
__global__ __launch_bounds__(256) void k_gemm(
    const float* __restrict__ A, const float* __restrict__ W,
    const float* __restrict__ bias, float* __restrict__ C,
    int M, int N, int K,
    const float* __restrict__ resid,
    const float* __restrict__ pos, const float* __restrict__ ltw,
    const float* __restrict__ ltb, const float* __restrict__ lead) {
  __shared__ float As[16][68];
  __shared__ float Ws[16][68];
  int m0 = blockIdx.y * 64, n0 = blockIdx.x * 64;
  int tid = threadIdx.x;
  int tx = tid & 15, ty = tid >> 4;
  int lr = tid & 63, lk = (tid >> 6) * 4;
  float acc[4][4] = {};
  for (int k0 = 0; k0 < K; k0 += 16) {
    float4 av = *(const float4*)(A + (size_t)(m0 + lr) * K + k0 + lk);
    float4 wv = {0.f, 0.f, 0.f, 0.f};
    if (n0 + lr < N) {
      wv = *(const float4*)(W + (size_t)(n0 + lr) * K + k0 + lk);
    }
    __syncthreads();
    As[lk + 0][lr] = av.x; As[lk + 1][lr] = av.y;
    As[lk + 2][lr] = av.z; As[lk + 3][lr] = av.w;
    Ws[lk + 0][lr] = wv.x; Ws[lk + 1][lr] = wv.y;
    Ws[lk + 2][lr] = wv.z; Ws[lk + 3][lr] = wv.w;
    __syncthreads();
#pragma unroll
    for (int kk = 0; kk < 16; kk++) {
      float4 a = *(const float4*)&As[kk][ty * 4];
      float4 b = *(const float4*)&Ws[kk][tx * 4];
      acc[0][0] += a.x * b.x; acc[0][1] += a.x * b.y; acc[0][2] += a.x * b.z; acc[0][3] += a.x * b.w;
      acc[1][0] += a.y * b.x; acc[1][1] += a.y * b.y; acc[1][2] += a.y * b.z; acc[1][3] += a.y * b.w;
      acc[2][0] += a.z * b.x; acc[2][1] += a.z * b.y; acc[2][2] += a.z * b.z; acc[2][3] += a.z * b.w;
      acc[3][0] += a.w * b.x; acc[3][1] += a.w * b.y; acc[3][2] += a.w * b.z; acc[3][3] += a.w * b.w;
    }
  }
#pragma unroll
  for (int ii = 0; ii < 4; ii++) {
    int m = m0 + ty * 4 + ii;
#pragma unroll
    for (int jj = 0; jj < 4; jj++) {
      int n = n0 + tx * 4 + jj;
      if (n >= N) continue;
      float v = acc[ii][jj] + bias[n];
      if (EPI == 1) v = 0.5f * v * (1.f + erff(v * 0.70710678118f));
      if (EPI == 2) v += resid[(size_t)m * N + n];
      if (EPI == 3) {
        int b = m >> 9, l = m & 511;
        v += pos[(size_t)l * 1024 + n] + ltw[n] * lead[b] + ltb[n];
      }
      C[(size_t)m * N + n] = v;
    }
  }
}

// ---------------------------------------------------------------------------
// LayerNorm over D=1024 (grid M). In-place safe.
// ---------------------------------------------------------------------------
__global__ __launch_bounds__(256) void k_ln(
    const float* __restrict__ src, const float* __restrict__ add,
    const float* __restrict__ g, const float* __restrict__ bb,
    float* __restrict__ dst) {
  __shared__ float red[8];
  int m = blockIdx.x, tid = threadIdx.x;
  float4 x = *(const float4*)(src + (size_t)m * 1024 + tid * 4);
  if (add) {
    float4 a2 = *(const float4*)(add + (size_t)m * 1024 + tid * 4);
    x.x += a2.x; x.y += a2.y; x.z += a2.z; x.w += a2.w;
  }
  float s1 = x.x + x.y + x.z + x.w;
  float s2 = x.x * x.x + x.y * x.y + x.z * x.z + x.w * x.w;
  for (int off = 1; off < 64; off <<= 1) {
    s1 += __shfl_xor(s1, off); s2 += __shfl_xor(s2, off);
  }
  if ((tid & 63) == 0) { red[(tid >> 6) * 2] = s1; red[(tid >> 6) * 2 + 1] = s2; }
  __syncthreads();
  s1 = red[0] + red[2] + red[4] + red[6];
  s2 = red[1] + red[3] + red[5] + red[7];
  float mean = s1 * (1.f / 1024.f);
  float var = s2 * (1.f / 1024.f) - mean * mean;
  float rstd = rsqrtf(var + EPSF);
  int c = tid * 4;
  float4 o;
  o.x = (x.x - mean) * rstd * g[c + 0] + bb[c + 0];
  o.y = (x.y - mean) * rstd * g[c + 1] + bb[c + 1];
  o.z = (x.z - mean) * rstd * g[c + 2] + bb[c + 2];
  o.w = (x.w - mean) * rstd * g[c + 3] + bb[c + 3];
  *(float4*)(dst + (size_t)m * 1024 + c) = o;
}

// ---------------------------------------------------------------------------
// Patch attention: per (b,h,ntile16). Two-pass softmax with S in LDS.
// ---------------------------------------------------------------------------
__global__ __launch_bounds__(256) void k_attn(
    const float* __restrict__ qkv, float* __restrict__ o) {
  __shared__ float Q[16][68];
  __shared__ float S[16][516];
  __shared__ float KV[32][68];
  int bid = blockIdx.x;
  int nt = bid & 31, h = (bid >> 5) & 15, b = bid >> 9;
  int tid = threadIdx.x;
  for (int i = tid; i < 16 * 64; i += 256) {
    int r = i >> 6, e = i & 63;
    Q[r][e] = qkv[(size_t)(b * 512 + nt * 16 + r) * 3072 + h * 64 + e];
  }
  __syncthreads();
  int r = tid >> 4, lane = tid & 15;
  for (int kt = 0; kt < 16; kt++) {
    for (int i = tid; i < 32 * 64; i += 256) {
      int rr = i >> 6, e = i & 63;
      KV[rr][e] = qkv[(size_t)(b * 512 + kt * 32 + rr) * 3072 + 1024 + h * 64 + e];
    }
    __syncthreads();
    for (int jj = lane; jj < 32; jj += 16) {
      float acc = 0.f;
#pragma unroll 8
      for (int e = 0; e < 64; e++) acc += Q[r][e] * KV[jj][e];
      S[r][kt * 32 + jj] = acc * 0.125f;
    }
    __syncthreads();
  }
  float mx = -1e30f;
  for (int j = lane; j < 512; j += 16) mx = fmaxf(mx, S[r][j]);
  for (int off = 1; off < 16; off <<= 1) mx = fmaxf(mx, __shfl_xor(mx, off));
  float sum = 0.f;
  for (int j = lane; j < 512; j += 16) {
    float e = __expf(S[r][j] - mx);
    S[r][j] = e; sum += e;
  }
  sum = red16(sum);
  float inv = 1.f / sum;
  int e0 = lane * 4;
  float4 accv = {0.f, 0.f, 0.f, 0.f};
  for (int kt = 0; kt < 16; kt++) {
    __syncthreads();
    for (int i = tid; i < 32 * 64; i += 256) {
      int rr = i >> 6, e = i & 63;
      KV[rr][e] = qkv[(size_t)(b * 512 + kt * 32 + rr) * 3072 + 2048 + h * 64 + e];
    }
    __syncthreads();
#pragma unroll 8
    for (int j = 0; j < 32; j++) {
      float p = S[r][kt * 32 + j] * inv;
      accv.x += p * KV[j][e0 + 0]; accv.y += p * KV[j][e0 + 1];
      accv.z += p * KV[j][e0 + 2]; accv.w += p * KV[j][e0 + 3];
    }
  }
  float* op = o + (size_t)(b * 512 + nt * 16 + r) * 1024 + h * 64 + e0;
  op[0] = accv.x; op[1] = accv.y; op[2] = accv.z; op[3] = accv.w;
}

// ---------------------------------------------------------------------------
// swz/swz8: bf16 LDS tile layout (v7/v9-verified), per 16-token group.
// ---------------------------------------------------------------------------
__device__ __forceinline__ int swz(int m, int c) {
  int g = c >> 3;
  g = (g & ~7) | ((g ^ m) & 7);
  return m * 1024 + g * 8 + (c & 7);
}
__device__ __forceinline__ int swz8(int m, int k) {  // k multiple of 8
  int g = k >> 3;
  g = (g & ~7) | ((g ^ m) & 7);
  return m * 1024 + g * 8;
}

// ---------------------------------------------------------------------------
// MFMA GEMM for f32 activations: C[1024][N] = A[1024][1024] @ Wblob^T + bias.
// Grid = (N/256 slices)*64 groups, bid = cs*64+g. 16 waves; wave wv stages
// token-row wv (f32->bf16->swz LDS) then computes col-tile ct=cs*16+wv.
// EPI: 0 plain, 1 gelu(exact), 2 +resid.
// ---------------------------------------------------------------------------
template <int EPI>
__global__ __launch_bounds__(1024) void k_mg(
    const float* __restrict__ A, const u16* __restrict__ blob,
    const float* __restrict__ bias, float* __restrict__ C, int N,
    const float* __restrict__ resid) {
  __shared__ __align__(16) u16 bufA[16 * 1024];
  int tid = threadIdx.x;
  int bid = blockIdx.x;
  int cs = bid >> 6, g = bid & 63;
  int wv = tid >> 6, lane = tid & 63;
  int row16 = lane & 15, quad = lane >> 4;
  // ---- stage A rows: wave wv loads token g*16+wv, lane cols [lane*16,+16) ----
  {
    const float* ar = A + (size_t)(g * 16 + wv) * 1024 + lane * 16;
#pragma unroll
    for (int q = 0; q < 4; q++) {
      float4 v = *(const float4*)(ar + q * 4);
      int c = lane * 16 + q * 4;
      bufA[swz(wv, c + 0)] = f2b(v.x); bufA[swz(wv, c + 1)] = f2b(v.y);
      bufA[swz(wv, c + 2)] = f2b(v.z); bufA[swz(wv, c + 3)] = f2b(v.w);
    }
  }
  __syncthreads();
  int ct = cs * 16 + wv;
  int n = cs * 256 + wv * 16 + row16;
  const u16* wb = blob + ((size_t)ct * 2048 + lane) * 8;
  f32x4 acc = {0.f, 0.f, 0.f, 0.f};
#pragma unroll
  for (int kk = 0; kk < 32; kk++) {
    bf16x8 wf = *(const bf16x8*)(wb + kk * 512);
    bf16x8 aF = *(const bf16x8*)(bufA + swz8(row16, kk * 32 + quad * 8));
    acc = __builtin_amdgcn_mfma_f32_16x16x32_bf16(aF, wf, acc, 0, 0, 0);
  }
  float bv = bias[n];
#pragma unroll
  for (int r = 0; r < 4; r++) {
    int tok = g * 16 + quad * 4 + r;
    float v = acc[r] + bv;
    if (EPI == 1) v = 0.5f * v * (1.f + erff(v * 0.70710678118f));
    if (EPI == 2) v += resid[(size_t)tok * 1024 + n];
    C[(size_t)tok * N + n] = v;
  }
}

// ---------------------------------------------------------------------------
// ODE kernels: fence-free kernel-per-phase (v13/v14-verified structure).
// k_og: v14 form (1 group/block). Grid 256 = 64 groups x 4 col-slices.
// PASS 1: h_img[swz] = bf16(relu(src@w1^T + b1))
// PASS 2: zraw[token][col] = f32(src@w2^T)
// ---------------------------------------------------------------------------
template <int PASS>
__global__ __launch_bounds__(1024) void k_og(
    const u16* __restrict__ wp, const float* __restrict__ bias,
    const u16* __restrict__ src_img, u16* __restrict__ h_img,
    float* __restrict__ zraw) {
  __shared__ __align__(16) u16 bufA[16 * 1024];
  int tid = threadIdx.x;
  int bid = blockIdx.x;
  int g = bid >> 2, cg = bid & 3;
  int wvid = tid >> 6, lane = tid & 63;
  int row16 = lane & 15, quad = lane >> 4;
  int n = cg * 256 + wvid * 16 + row16;  // this lane's output column
  int ct = cg * 16 + wvid;               // global col-tile 0..63
  const u16* wb = wp + ((size_t)ct * 2048 + lane) * 8;  // packed frag base
  // ---- stage activation image (32KB) -> LDS (per-lane src, linear dst) ----
  {
    const u16* src = src_img + (size_t)g * 16384 + wvid * 1024 + lane * 8;
    u16* dst = bufA + wvid * 1024;
    __builtin_amdgcn_global_load_lds(
        (const __attribute__((address_space(1))) uint32_t*)src,
        (__attribute__((address_space(3))) uint32_t*)dst, 16, 0, 0);
    __builtin_amdgcn_global_load_lds(
        (const __attribute__((address_space(1))) uint32_t*)(src + 512),
        (__attribute__((address_space(3))) uint32_t*)(dst + 512), 16, 0, 0);
  }
  VMCNT(0);
  __syncthreads();
  // ---- MFMA K-loop (v9-verified fragment path) ----
  f32x4 acc = {0.f, 0.f, 0.f, 0.f};
#pragma unroll
  for (int kk = 0; kk < 32; kk++) {
    bf16x8 wf = *(const bf16x8*)(wb + kk * 512);
    bf16x8 aF = *(const bf16x8*)(bufA + swz8(row16, kk * 32 + quad * 8));
    acc = __builtin_amdgcn_mfma_f32_16x16x32_bf16(aF, wf, acc, 0, 0, 0);
  }
  if (PASS == 1) {
    float bv = bias[n];
#pragma unroll
    for (int r = 0; r < 4; r++) {
      int ml = quad * 4 + r;
      h_img[(size_t)g * 16384 + swz(ml, n)] = f2b(fmaxf(acc[r] + bv, 0.f));
    }
  } else {
#pragma unroll
    for (int r = 0; r < 4; r++) {
      int tok = g * 16 + quad * 4 + r;
      zraw[(size_t)tok * 1024 + n] = acc[r];
    }
  }
}

// Init: y = xs; act image = bf16(xs); out = xs. Grid 1024 (token/block).
__global__ __launch_bounds__(256) void k_odeinit(
    const float* __restrict__ xs, float* __restrict__ y,
    u16* __restrict__ act_img, float* __restrict__ out) {
  int t = blockIdx.x, tid = threadIdx.x;
  int c = tid * 4;
  int g = t >> 4, ml = t & 15;
  float4 v = *(const float4*)(xs + (size_t)t * 1024 + c);
  *(float4*)(y + (size_t)t * 1024 + c) = v;
  *(float4*)(out + (size_t)t * 1024 + c) = v;
  u16* ag = act_img + (size_t)g * 16384;
  ag[swz(ml, c + 0)] = f2b(v.x); ag[swz(ml, c + 1)] = f2b(v.y);
  ag[swz(ml, c + 2)] = f2b(v.z); ag[swz(ml, c + 3)] = f2b(v.w);
}

// RK4 + LN epilogue. Grid 1024 (token/block), 256 thr.
// v16: residual read as bf16 from act image (v7-v12 verified arithmetic);
// nvf f32 copy eliminated (saves 8MB/phase).
__global__ __launch_bounds__(256) void k_rk4(
    const float* __restrict__ zraw, const float* __restrict__ b2,
    const float* __restrict__ ng, const float* __restrict__ nb,
    float* __restrict__ y, float* __restrict__ accr,
    u16* __restrict__ act_img, float* __restrict__ out,
    const float* __restrict__ lead, int s, int ph) {
  __shared__ float red[8];
  int t = blockIdx.x, tid = threadIdx.x;
  int c = tid * 4;
  int g = t >> 4, ml = t & 15;
  u16* ag = act_img + (size_t)g * 16384;
  float4 zr = *(const float4*)(zraw + (size_t)t * 1024 + c);
  float4 bb = *(const float4*)(b2 + c);
  // residual: bf16 act image, cols c..c+3 are consecutive u16 (same 8-block)
  ushort4 nv4 = *(const ushort4*)(ag + swz(ml, c));
  float z0 = zr.x + bb.x + b2f(nv4.x), z1 = zr.y + bb.y + b2f(nv4.y);
  float z2 = zr.z + bb.z + b2f(nv4.z), z3 = zr.w + bb.w + b2f(nv4.w);
  float s1 = z0 + z1 + z2 + z3;
  float s2 = z0 * z0 + z1 * z1 + z2 * z2 + z3 * z3;
  for (int off = 1; off < 64; off <<= 1) {
    s1 += __shfl_xor(s1, off); s2 += __shfl_xor(s2, off);
  }
  if ((tid & 63) == 0) { red[(tid >> 6) * 2] = s1; red[(tid >> 6) * 2 + 1] = s2; }
  __syncthreads();
  s1 = red[0] + red[2] + red[4] + red[6];
  s2 = red[1] + red[3] + red[5] + red[7];
  float mean = s1 * (1.f / 1024.f);
  float var = s2 * (1.f / 1024.f) - mean * mean;
  float rstd = rsqrtf(var + EPSF);
  float4 gv = *(const float4*)(ng + c);
  float4 bv = *(const float4*)(nb + c);
  float k0 = (z0 - mean) * rstd * gv.x + bv.x;
  float k1 = (z1 - mean) * rstd * gv.y + bv.y;
  float k2 = (z2 - mean) * rstd * gv.z + bv.z;
  float k3 = (z3 - mean) * rstd * gv.w + bv.w;
  float4 yv = *(const float4*)(y + (size_t)t * 1024 + c);
  float4 ac;
  float cf = (ph < 2) ? 0.5f * RESF : RESF;
  const float h6 = RESF / 6.0f;
  float4 nn;
  if (ph == 0) {
    ac.x = k0; ac.y = k1; ac.z = k2; ac.w = k3;
    nn.x = yv.x + cf * k0; nn.y = yv.y + cf * k1;
    nn.z = yv.z + cf * k2; nn.w = yv.w + cf * k3;
    *(float4*)(accr + (size_t)t * 1024 + c) = ac;
  } else if (ph < 3) {
    ac = *(const float4*)(accr + (size_t)t * 1024 + c);
    ac.x += 2.f * k0; ac.y += 2.f * k1; ac.z += 2.f * k2; ac.w += 2.f * k3;
    nn.x = yv.x + cf * k0; nn.y = yv.y + cf * k1;
    nn.z = yv.z + cf * k2; nn.w = yv.w + cf * k3;
    *(float4*)(accr + (size_t)t * 1024 + c) = ac;
  } else {
    ac = *(const float4*)(accr + (size_t)t * 1024 + c);
    yv.x += h6 * (ac.x + k0); yv.y += h6 * (ac.y + k1);
    yv.z += h6 * (ac.z + k2); yv.w += h6 * (ac.w + k3);
    nn = yv;
    *(float4*)(y + (size_t)t * 1024 + c) = yv;
    int idxb = (int)roundf(lead[t >> 9] * 100.0f);
    if ((s + 1) == idxb)
      *(float4*)(out + (size_t)t * 1024 + c) = yv;
  }
  ag[swz(ml, c + 0)] = f2b(nn.x); ag[swz(ml, c + 1)] = f2b(nn.y);
  ag[swz(ml, c + 2)] = f2b(nn.z); ag[swz(ml, c + 3)] = f2b(nn.w);
}

// ---------------------------------------------------------------------------
// Unpatchify: y3[m][p*10+q*5+c] -> out[b][c][hh*2+p][ww*2+q], FLOAT32
// ---------------------------------------------------------------------------
__global__ __launch_bounds__(256) void k_unpatch(
    const float* __restrict__ y3, float* __restrict__ outp) {
  int o = blockIdx.x * 256 + threadIdx.x;
  if (o >= 20480) return;
  int b = o / 10240;
  int c = (o / 2048) % 5;
  int hrow = (o / 64) % 32;
  int wcol = o % 64;
  int hh = hrow >> 1, p = hrow & 1, ww = wcol >> 1, q = wcol & 1;
  int m2 = b * 512 + hh * 32 + ww;
  int colj = p * 10 + q * 5 + c;
  outp[o] = y3[(size_t)m2 * 20 + colj];
}

// ===========================================================================
extern "C" void kernel_launch(void* const* d_in, const int* in_sizes, int n_in,
                              void* d_out, int out_size, void* d_ws, size_t ws_size,
                              hipStream_t stream) {
  const float* x         = (const float*)d_in[0];
  const float* lead      = (const float*)d_in[1];
  const float* patch_w   = (const float*)d_in[2];
  const float* patch_b   = (const float*)d_in[3];
  const float* var_embed = (const float*)d_in[4];
  const float* var_query = (const float*)d_in[5];
  const float* agg_in_w  = (const float*)d_in[6];
  const float* agg_in_b  = (const float*)d_in[7];
  const float* agg_out_w = (const float*)d_in[8];
  const float* agg_out_b = (const float*)d_in[9];
  const float* pos_embed = (const float*)d_in[10];
  const float* lt_w      = (const float*)d_in[11];
  const float* lt_b      = (const float*)d_in[12];
  const float* blk_qkv_w = (const float*)d_in[13];
  const float* blk_qkv_b = (const float*)d_in[14];
  const float* blk_out_w = (const float*)d_in[15];
  const float* blk_out_b = (const float*)d_in[16];
  const float* blk_n1_g  = (const float*)d_in[17];
  const float* blk_n1_b  = (const float*)d_in[18];
  const float* blk_n2_g  = (const float*)d_in[19];
  const float* blk_n2_b  = (const float*)d_in[20];
  const float* ode_w1    = (const float*)d_in[21];
  const float* ode_b1    = (const float*)d_in[22];
  const float* ode_w2    = (const float*)d_in[23];
  const float* ode_b2    = (const float*)d_in[24];
  const float* ode_ng    = (const float*)d_in[25];
  const float* ode_nb    = (const float*)d_in[26];
  const float* norm_g    = (const float*)d_in[27];
  const float* norm_b    = (const float*)d_in[28];
  const float* h1_w      = (const float*)d_in[29];
  const float* h1_b      = (const float*)d_in[30];
  const float* h2_w      = (const float*)d_in[31];
  const float* h2_b      = (const float*)d_in[32];
  const float* hf_w      = (const float*)d_in[33];
  const float* hf_b      = (const float*)d_in[34];
  (void)in_sizes; (void)n_in; (void)out_size; (void)ws_size;

  float* ws = (float*)d_ws;
  // ODE buffers in ode-dead regions (qkv/attno/t1):
  u16*   act16 = (u16*)(ws + 0);        // 2MB act image
  u16*   h16   = (u16*)(ws + 524288);   // 2MB h image
  float* zraw  = ws + 1048576;          // 4MB raw GEMM2 out
  float* ybuf  = ws + 2097152;          // 4MB RK4 y      (end 3145728)
  float* accr  = ws + 3145728;          // 4MB RK4 accum  (attno region)
  float* patches = ws + 0;         // 20480 (stage-1 only; dead before ode)
  float* qvec    = ws + 20480;     // 1024
  float* qb      = ws + 21504;     // 256 (16 used)
  float* u       = ws + 21760;     // 16384
  float* PU      = ws + 38144;     // 320
  float* C0      = ws + 38464;     // 80 (pad to 40960)
  float* amat    = ws + 40960;     // 81920
  float* PW      = ws + 122880;    // 20480
  float* CV      = ws + 143360;    // 5120  (end 148480)
  float* agg     = ws + 3145728;   // 1048576 (attno slot; dead by then)
  float* qkv   = ws + 0;           // 3145728
  float* attno = ws + 3145728;     // 1048576
  float* t1    = ws + 4194304;     // 1048576
  float* odeo  = ws + 5242880;     // 1048576
  float* xs    = ws + 6291456;     // 1048576
  u16*   w16a  = (u16*)(ws + 7340032);  // packed ode w1 (bf16 frag blob)
  u16*   w16b  = (u16*)(ws + 7864320);  // packed ode w2
  // transient GEMM weight blobs (lifetimes verified against region uses):
  u16*   qkvblob = (u16*)(ws + 3145728); // 6MB in attno+t1 (dead until attn)
  u16*   aoblob  = (u16*)(ws + 5242880); // 2MB in odeo (dead until ODE init)
  u16*   hblob   = (u16*)(ws + 3145728); // 2MB in attno region (head only)
  float* y1 = ws + 0;
  float* y2 = ws + 1048576;
  float* y3 = ws + 2097152;        // 20480

  // ---- stage 1 ----
  k_patches<<<dim3(80), dim3(256), 0, stream>>>(x, patches);
  k_qvec<<<dim3(64), dim3(256), 0, stream>>>(var_query, agg_in_w, agg_in_b, qvec);
  k_qb<<<dim3(1), dim3(256), 0, stream>>>(qvec, agg_in_b + 1024, qb);
  k_u<<<dim3(64), dim3(256), 0, stream>>>(qvec, agg_in_w + (size_t)1024 * 1024, u);
  k_pu<<<dim3(80), dim3(256), 0, stream>>>(patch_w, patch_b, var_embed, u, qb, PU, C0);
  k_pw<<<dim3(5120), dim3(256), 0, stream>>>(
      agg_in_w + (size_t)2048 * 1024, agg_in_b + 2048, patch_w, patch_b,
      var_embed, PW, CV);
  k_scoresm<<<dim3(1024), dim3(256), 0, stream>>>(patches, PU, C0, amat);
  k_agg<<<dim3(1024), dim3(256), 0, stream>>>(patches, PW, CV, amat, agg);
  k_gemm<3><<<dim3(16, 16), dim3(256), 0, stream>>>(
      agg, agg_out_w, agg_out_b, xs, 1024, 1024, 1024,
      nullptr, pos_embed, lt_w, lt_b, lead);

  // ---- transformer blocks ----
  for (int i = 0; i < 2; i++) {
    // qkv = xs @ Wqkv^T + b  (bf16 MFMA; blob in attno+t1, dead until attn)
    k_pack<<<dim3(12288), dim3(256), 0, stream>>>(
        blk_qkv_w + (size_t)i * 3072 * 1024, qkvblob);
    k_mg<0><<<dim3(768), dim3(1024), 0, stream>>>(
        xs, qkvblob, blk_qkv_b + i * 3072, qkv, 3072, nullptr);
    k_attn<<<dim3(1024), dim3(256), 0, stream>>>(qkv, attno);
    // t1 = attno @ Wout^T + b + xs  (bf16 MFMA; blob in odeo region)
    k_pack<<<dim3(4096), dim3(256), 0, stream>>>(
        blk_out_w + (size_t)i * 1048576, aoblob);
    k_mg<2><<<dim3(256), dim3(1024), 0, stream>>>(
        attno, aoblob, blk_out_b + i * 1024, t1, 1024, xs);
    k_ln<<<dim3(1024), dim3(256), 0, stream>>>(
        t1, (const float*)nullptr, blk_n1_g + i * 1024, blk_n1_b + i * 1024, xs);
    k_pack<<<dim3(4096), dim3(256), 0, stream>>>(
        ode_w1 + (size_t)i * 1048576, w16a);
    k_pack<<<dim3(4096), dim3(256), 0, stream>>>(
        ode_w2 + (size_t)i * 1048576, w16b);
    // ---- fence-free ODE: 3 kernels per RK4 phase (v13/v14 structure) ----
    k_odeinit<<<dim3(1024), dim3(256), 0, stream>>>(xs, ybuf, act16, odeo);
    for (int s = 0; s < NSTEPS; s++) {
      for (int ph = 0; ph < 4; ph++) {
        k_og<1><<<dim3(256), dim3(1024), 0, stream>>>(
            w16a, ode_b1 + i * 1024, act16, h16, nullptr);
        k_og<2><<<dim3(256), dim3(1024), 0, stream>>>(
            w16b, nullptr, h16, nullptr, zraw);
        k_rk4<<<dim3(1024), dim3(256), 0, stream>>>(
            zraw, ode_b2 + i * 1024, ode_ng + i * 1024, ode_nb + i * 1024,
            ybuf, accr, act16, odeo, lead, s, ph);
      }
    }
    k_ln<<<dim3(1024), dim3(256), 0, stream>>>(
        xs, odeo, blk_n2_g + i * 1024, blk_n2_b + i * 1024, xs);
  }

  // ---- head ----
  k_ln<<<dim3(1024), dim3(256), 0, stream>>>(
      xs, (const float*)nullptr, norm_g, norm_b, xs);
  k_pack<<<dim3(4096), dim3(256), 0, stream>>>(h1_w, hblob);
  k_mg<1><<<dim3(256), dim3(1024), 0, stream>>>(
      xs, hblob, h1_b, y1, 1024, nullptr);
  k_pack<<<dim3(4096), dim3(256), 0, stream>>>(h2_w, hblob);
  k_mg<1><<<dim3(256), dim3(1024), 0, stream>>>(
      y1, hblob, h2_b, y2, 1024, nullptr);
  k_gemm<0><<<dim3(1, 16), dim3(256), 0, stream>>>(
      y2, hf_w, hf_b, y3, 1024, 20, 1024, nullptr, nullptr, nullptr, nullptr, nullptr);
  k_unpatch<<<dim3(80), dim3(256), 0, stream>>>(y3, (float*)d_out);
}